// Round 1
// baseline (194.898 us; speedup 1.0000x reference)
//
#include <hip/hip_runtime.h>
#include <math.h>

#define BATCH 64
#define TLEN 2048
#define DIM 80
#define TILE_T 16
#define NROWS (TILE_T + 2)          // staged rows incl. +-1 halo
#define LDSW 88                     // LDS row stride (floats): data at [4,84), zeros at 3 and 84
#define THREADS 320                 // 5 waves; 20 threads/row * 16 rows
#define TILES_PER_B (TLEN / TILE_T)

// Smooth-min constant: K=32; c = K * log2(e)
#define SMIN_C  46.166241308446828f
#define SMIN_RC 0.02166084939249829f   // 1/c

__global__ __launch_bounds__(THREADS) void jitter_kernel(
    const float* __restrict__ inp, const float* __restrict__ tgt,
    float* __restrict__ out)
{
    __shared__ float lds[NROWS * LDSW];
    __shared__ float wsum[THREADS / 64];

    const int bx  = blockIdx.x;
    const int b   = bx / TILES_PER_B;
    const int t0  = (bx % TILES_PER_B) * TILE_T;
    const int tid = threadIdx.x;

    // ---- stage target rows [t0-1, t0+16] into LDS (zero pad OOB rows) ----
    for (int i = tid; i < NROWS * (DIM / 4); i += THREADS) {
        const int r  = i / (DIM / 4);
        const int c4 = i % (DIM / 4);
        const int t  = t0 - 1 + r;
        float4 v = make_float4(0.f, 0.f, 0.f, 0.f);
        if (t >= 0 && t < TLEN) {
            v = *(const float4*)(tgt + ((size_t)(b * TLEN + t) * DIM + c4 * 4));
        }
        *(float4*)(&lds[r * LDSW + 4 + c4 * 4]) = v;   // 16B aligned: 88r+4+4c4 ≡ 0 (mod 4)
    }
    // zero halo columns (d = -1 and d = 80)
    if (tid < NROWS) {
        lds[tid * LDSW + 3] = 0.f;
        lds[tid * LDSW + 4 + DIM] = 0.f;
    }
    __syncthreads();

    // ---- each thread: 4 consecutive d in one t-row ----
    const int rloc = tid / 20;       // 0..15 (local t-row)
    const int d0   = (tid % 20) * 4; // 0..76
    const float4 in4 = *(const float4*)(inp + ((size_t)(b * TLEN + t0 + rloc) * DIM + d0));
    const float inv[4] = {in4.x, in4.y, in4.z, in4.w};

    // 3 tgt rows x 6 floats (covers d0-1 .. d0+4)
    float g[3][6];
#pragma unroll
    for (int r = 0; r < 3; ++r) {
        const int base = (rloc + r) * LDSW + 3 + d0;
#pragma unroll
        for (int i = 0; i < 6; ++i) g[r][i] = lds[base + i];
    }

    float acc = 0.f;
#pragma unroll
    for (int e = 0; e < 4; ++e) {
        const float x = inv[e];
        float v[9];
#pragma unroll
        for (int r = 0; r < 3; ++r)
#pragma unroll
            for (int i = 0; i < 3; ++i)
                v[r * 3 + i] = fabsf(x - g[r][e + i]);

        const float center = v[4];   // (dy,dx) = (0,0)
        float m = fminf(fminf(fminf(v[0], v[1]), fminf(v[2], v[3])),
                        fminf(fminf(v[4], v[5]), fminf(v[6], v[7])));
        m = fminf(m, v[8]);

        float S = 0.f;
#pragma unroll
        for (int s = 0; s < 9; ++s)
            S += __builtin_amdgcn_exp2f(SMIN_C * (m - v[s]));  // args <= 0, S in [1,9]

        const float sm = m - __builtin_amdgcn_logf(S) * SMIN_RC; // logf builtin = log2
        acc += center + sm;
    }

    // ---- reduction: wave shuffle -> LDS -> one atomic per block ----
#pragma unroll
    for (int off = 32; off > 0; off >>= 1)
        acc += __shfl_down(acc, off, 64);
    const int lane = tid & 63, wid = tid >> 6;
    if (lane == 0) wsum[wid] = acc;
    __syncthreads();
    if (tid == 0) {
        float tot = 0.f;
#pragma unroll
        for (int w = 0; w < THREADS / 64; ++w) tot += wsum[w];
        // loss = 0.5 * (mean(center) + mean(sm)) = sum(center+sm) * 0.5/N
        atomicAdd(out, tot * (0.5f / (float)(BATCH * TLEN * DIM)));
    }
}

__global__ void zero_kernel(float* out, int n) {
    const int i = blockIdx.x * blockDim.x + threadIdx.x;
    if (i < n) out[i] = 0.f;
}

extern "C" void kernel_launch(void* const* d_in, const int* in_sizes, int n_in,
                              void* d_out, int out_size, void* d_ws, size_t ws_size,
                              hipStream_t stream) {
    const float* inp = (const float*)d_in[0];
    const float* tgt = (const float*)d_in[1];
    float* out = (float*)d_out;

    zero_kernel<<<1, 64, 0, stream>>>(out, out_size);
    jitter_kernel<<<BATCH * TILES_PER_B, THREADS, 0, stream>>>(inp, tgt, out);
}

// Round 2
// 112.078 us; speedup vs baseline: 1.7390x; 1.7390x over previous
//
#include <hip/hip_runtime.h>
#include <math.h>

#define BATCH 64
#define TLEN 2048
#define DIM 80
#define DQ (DIM / 4)          // 20 float4-quads per row
#define TT 8                  // t-rows per thread strip
#define TCHUNKS (TLEN / TT)   // 256
#define THREADS 256
#define NSTRIPS (BATCH * TCHUNKS * DQ)        // 327680 threads
#define NBLOCKS (NSTRIPS / THREADS)           // 1280

// Smooth-min: K=32; c = K*log2(e)
#define SMIN_C  46.166241308446828f
#define SMIN_RC 0.02166084939249829f   // 1/c

__device__ __forceinline__ void load_row(float r[6], const float* __restrict__ base,
                                         int t, int q) {
    // base points at tgt[b][0][d0]; fills r[0]=d0-1, r[1..4]=d0..d0+3, r[5]=d0+4
    if (t >= 0 && t < TLEN) {
        const float* p = base + (size_t)t * DIM;
        const float4 v = *(const float4*)p;
        r[0] = (q > 0)      ? p[-1] : 0.f;
        r[1] = v.x; r[2] = v.y; r[3] = v.z; r[4] = v.w;
        r[5] = (q < DQ - 1) ? p[4]  : 0.f;
    } else {
#pragma unroll
        for (int i = 0; i < 6; ++i) r[i] = 0.f;
    }
}

__device__ __forceinline__ float elem_loss(float x, const float* rm, const float* r0,
                                           const float* rp, int e) {
    float v[9];
#pragma unroll
    for (int i = 0; i < 3; ++i) {
        v[0 + i] = fabsf(x - rm[e + i]);
        v[3 + i] = fabsf(x - r0[e + i]);
        v[6 + i] = fabsf(x - rp[e + i]);
    }
    const float center = v[4];
    float m = fminf(fminf(fminf(v[0], v[1]), fminf(v[2], v[3])),
                    fminf(fminf(v[4], v[5]), fminf(v[6], v[7])));
    m = fminf(m, v[8]);
    float S = 0.f;
#pragma unroll
    for (int s = 0; s < 9; ++s)
        S += __builtin_amdgcn_exp2f(SMIN_C * (m - v[s]));   // args <= 0; S in [1,9]
    const float sm = m - __builtin_amdgcn_logf(S) * SMIN_RC; // logf builtin = log2
    return center + sm;
}

__global__ __launch_bounds__(THREADS) void jitter_kernel(
    const float* __restrict__ inp, const float* __restrict__ tgt,
    float* __restrict__ ws)
{
    __shared__ float wsum[THREADS / 64];

    const int n   = blockIdx.x * THREADS + threadIdx.x;
    const int q   = n % DQ;
    const int rem = n / DQ;
    const int tc  = rem % TCHUNKS;
    const int b   = rem / TCHUNKS;
    const int t0  = tc * TT;
    const int d0  = q * 4;

    const float* tgb = tgt + (size_t)b * TLEN * DIM + d0;
    const float* inb = inp + (size_t)b * TLEN * DIM + d0;

    float rm[6], r0[6], rp[6];
    load_row(rm, tgb, t0 - 1, q);
    load_row(r0, tgb, t0,     q);

    float acc = 0.f;
#pragma unroll
    for (int lt = 0; lt < TT; ++lt) {
        load_row(rp, tgb, t0 + lt + 1, q);
        const float4 in4 = *(const float4*)(inb + (size_t)(t0 + lt) * DIM);
        acc += elem_loss(in4.x, rm, r0, rp, 0);
        acc += elem_loss(in4.y, rm, r0, rp, 1);
        acc += elem_loss(in4.z, rm, r0, rp, 2);
        acc += elem_loss(in4.w, rm, r0, rp, 3);
#pragma unroll
        for (int i = 0; i < 6; ++i) { rm[i] = r0[i]; r0[i] = rp[i]; }
    }

    // block reduction -> one partial per block (no atomics, no pre-zero needed)
#pragma unroll
    for (int off = 32; off > 0; off >>= 1)
        acc += __shfl_down(acc, off, 64);
    const int lane = threadIdx.x & 63, wid = threadIdx.x >> 6;
    if (lane == 0) wsum[wid] = acc;
    __syncthreads();
    if (threadIdx.x == 0) {
        float tot = 0.f;
#pragma unroll
        for (int w = 0; w < THREADS / 64; ++w) tot += wsum[w];
        ws[blockIdx.x] = tot;
    }
}

__global__ __launch_bounds__(256) void reduce_kernel(const float* __restrict__ ws,
                                                     float* __restrict__ out) {
    __shared__ float wsum[4];
    float s = 0.f;
    for (int i = threadIdx.x; i < NBLOCKS; i += 256) s += ws[i];
#pragma unroll
    for (int off = 32; off > 0; off >>= 1)
        s += __shfl_down(s, off, 64);
    const int lane = threadIdx.x & 63, wid = threadIdx.x >> 6;
    if (lane == 0) wsum[wid] = s;
    __syncthreads();
    if (threadIdx.x == 0) {
        float tot = wsum[0] + wsum[1] + wsum[2] + wsum[3];
        out[0] = tot * (0.5f / (float)((size_t)BATCH * TLEN * DIM));
    }
}

extern "C" void kernel_launch(void* const* d_in, const int* in_sizes, int n_in,
                              void* d_out, int out_size, void* d_ws, size_t ws_size,
                              hipStream_t stream) {
    const float* inp = (const float*)d_in[0];
    const float* tgt = (const float*)d_in[1];
    float* ws  = (float*)d_ws;
    float* out = (float*)d_out;

    jitter_kernel<<<NBLOCKS, THREADS, 0, stream>>>(inp, tgt, ws);
    reduce_kernel<<<1, 256, 0, stream>>>(ws, out);
}